// Round 9
// baseline (178.351 us; speedup 1.0000x reference)
//
#include <hip/hip_runtime.h>
#include <hip/hip_fp16.h>
#include <math.h>

// SPAIRPointFeatureNetwork on MI355X.
//   h_{p,j} = Q[j] - G[p];  celu monotonic => segmax(celu(h)) = celu(max_j Q[j] - G[p]).
//
// Ledger: R7 (5-disp unsorted)=177.0; R10 (2x occ)=178.0; R11 (9-disp
//   sorted)=177.2; R15 (ushort idx)=176.5  => four different chains, same
//   time: a structural floor. Warm kernel sum (R12/R14 REP): ~85us. Missing
//   ~80us ~= 9 dispatch boundaries x (launch gap 1.6us + XCD-L2
//   flush/invalidate ~5-10us when MBs dirty). R14 FETCH: layer3 re-fetches
//   its whole working set每rep => no cross-phase cache retention. Also L2
//   layer anomaly: 41us, VALUBusy 52%, finish = ~800 serial fmaf on 32/256
//   lanes.
// R16 (this): (1) 9->7 dispatches: k_trans fused INTO layer1 (reads old idx
//   via order, perm-translates, emits idxs for L2/L3; saves a 16MB pass and
//   a boundary). (2) L1/L2 finish parallelized 4x: x staged in padded LDS,
//   qnext split across 2/4 lanes/point (layer3-style, which is the faster
//   layer). Predict 177 -> 150-165. PRE-COMMIT: if 177±3 again, the external
//   floor is confirmed -> declare ROOFLINE next round.

#define NPTS 65536
#define KNBR 64
#define TILE 32
#define NCELL 4096

__device__ __forceinline__ float celu1(float x) {
    return x > 0.0f ? x : (__expf(x) - 1.0f);
}

__device__ __forceinline__ unsigned pkmax(unsigned a, unsigned b) {
    unsigned d;
    asm("v_pk_max_f16 %0, %1, %2" : "=v"(d) : "v"(a), "v"(b));
    return d;
}

__device__ __forceinline__ unsigned pack2(float a, float b) {
    __half2 h = __floats2half2_rn(a, b);
    return *(unsigned*)&h;
}

// ---- sort infra -----------------------------------------------------------

__global__ __launch_bounds__(256) void k_cell(
    const float* __restrict__ pos, float* __restrict__ dout, int out_size,
    int* __restrict__ cid, int* __restrict__ hist)
{
    int t = blockIdx.x * 256 + threadIdx.x;
    if (t < NPTS) {
        float p0 = pos[3 * t + 0];
        float p1 = pos[3 * t + 1];
        float p2 = pos[3 * t + 2];
        dout[3 * t + 0] = p0;
        dout[3 * t + 1] = p1;
        dout[3 * t + 2] = p2;
        int cx = min((int)(p0 * 16.0f), 15);
        int cy = min((int)(p1 * 16.0f), 15);
        int cz = min((int)(p2 * 16.0f), 15);
        int c = (cx * 16 + cy) * 16 + cz;
        cid[t] = c;
        atomicAdd(&hist[c], 1);
        for (int j = 35 * NPTS + t; j < out_size; j += NPTS)
            dout[j] = 0.0f;
    }
}

__global__ __launch_bounds__(64) void k_scan(
    const int* __restrict__ hist, int* __restrict__ cellptr)
{
    int l = threadIdx.x;
    int v[64];
    int s = 0;
#pragma unroll
    for (int i = 0; i < 64; ++i) { v[i] = s; s += hist[l * 64 + i]; }
    int run = s;
#pragma unroll
    for (int st = 1; st < 64; st <<= 1) {
        int o = __shfl_up(run, st, 64);
        if (l >= st) run += o;
    }
    int off = run - s;
#pragma unroll
    for (int i = 0; i < 64; ++i)
        cellptr[l * 64 + i] = off + v[i];
}

__global__ __launch_bounds__(256) void k_scatter(
    const float* __restrict__ pos, const int* __restrict__ cid,
    int* __restrict__ cellptr, unsigned short* __restrict__ perm,
    int* __restrict__ order, float* __restrict__ pos_s,
    const float* __restrict__ w1a, const float* __restrict__ b1a,
    __half* __restrict__ q1s)
{
    int t = blockIdx.x * 256 + threadIdx.x;
    if (t >= NPTS) return;
    int c = cid[t];
    int nid = atomicAdd(&cellptr[c], 1);
    perm[t] = (unsigned short)nid;
    order[nid] = t;
    float p0 = pos[3 * t + 0];
    float p1 = pos[3 * t + 1];
    float p2 = pos[3 * t + 2];
    pos_s[3 * nid + 0] = p0;
    pos_s[3 * nid + 1] = p1;
    pos_s[3 * nid + 2] = p2;
    float q[8];
#pragma unroll
    for (int ch = 0; ch < 8; ++ch) {
        float a = b1a[ch];
        a = fmaf(p0, w1a[0 * 8 + ch] + w1a[3 * 8 + ch], a);
        a = fmaf(p1, w1a[1 * 8 + ch] + w1a[4 * 8 + ch], a);
        a = fmaf(p2, w1a[2 * 8 + ch] + w1a[5 * 8 + ch], a);
        q[ch] = a;
    }
    uint4 pk;
    pk.x = pack2(q[0], q[1]);
    pk.y = pack2(q[2], q[3]);
    pk.z = pack2(q[4], q[5]);
    pk.w = pack2(q[6], q[7]);
    *(uint4*)(q1s + 8 * nid) = pk;
}

// ---- fused layer (sorted space, ushort ids) -------------------------------
// FUSE: layer1 also performs the idx translation (reads old-space idx via
// order/perm, writes ushort idxs for layers 2/3).
// Finish (FHN>0): x computed by QW lanes/point, staged in padded LDS,
// qnext channels split QW ways (parallel, layer3-style).
template <int FH, int FOUT, int FHN, bool WRITEX, bool FUSE>
__global__ __launch_bounds__(256, 8) void k_layer(
    const __half* __restrict__ q,             // N x FH (fp16, sorted)
    const unsigned short* __restrict__ idx,   // N x 64 ushort (null if FUSE)
    const int* __restrict__ idx_old,          // N x 64 int, old space (FUSE)
    unsigned short* __restrict__ idxs_out,    // ushort idx out (FUSE)
    const unsigned short* __restrict__ perm,  // old->new (FUSE)
    const float* __restrict__ pos,            // sorted pos
    const int* __restrict__ order,            // new->old
    const float* __restrict__ wap,
    const float* __restrict__ wb,
    const float* __restrict__ bb,
    const float* __restrict__ wan,
    const float* __restrict__ ban,
    float* __restrict__ xout,
    __half* __restrict__ qnext)
{
    constexpr int SL  = FH / 8;
    constexpr int LPP = SL * 8;
    constexpr int PPW = 64 / LPP;
    constexpr int NIT = TILE / (4 * PPW);
    constexpr int QW  = (FOUT >= 16) ? 4 : 2;   // finish lanes per point

    __shared__ uint4 m_lds[TILE * SL];
    __shared__ float x_lds[(FHN > 0) ? TILE * (FOUT + 1) : 1];

    int w  = threadIdx.x >> 6;
    int l  = threadIdx.x & 63;
    int pl = l / LPP;
    int u  = l % LPP;
    int c  = u % SL;
    int g  = u / SL;
    int tb = (blockIdx.x & 255) * (NPTS / TILE / 256) + (blockIdx.x >> 8);
    int pbase = tb * TILE;

#pragma unroll
    for (int it = 0; it < NIT; ++it) {
        int lp = it * (4 * PPW) + w * PPW + pl;
        int p  = pbase + lp;
        int e0, e1, e2, e3, e4, e5, e6, e7;
        if constexpr (FUSE) {
            int old = order[p];
            const int4* src = (const int4*)(idx_old + old * KNBR + g * 8);
            int4 v0 = src[0];
            int4 v1 = src[1];
            e0 = perm[v0.x]; e1 = perm[v0.y]; e2 = perm[v0.z]; e3 = perm[v0.w];
            e4 = perm[v1.x]; e5 = perm[v1.y]; e6 = perm[v1.z]; e7 = perm[v1.w];
            uint4 o;
            o.x = (unsigned)e0 | ((unsigned)e1 << 16);
            o.y = (unsigned)e2 | ((unsigned)e3 << 16);
            o.z = (unsigned)e4 | ((unsigned)e5 << 16);
            o.w = (unsigned)e6 | ((unsigned)e7 << 16);
            *(uint4*)(idxs_out + p * KNBR + g * 8) = o;
        } else {
            uint4 iv = *(const uint4*)(idx + p * KNBR + g * 8);
            e0 = iv.x & 0xffff; e1 = iv.x >> 16;
            e2 = iv.y & 0xffff; e3 = iv.y >> 16;
            e4 = iv.z & 0xffff; e5 = iv.z >> 16;
            e6 = iv.w & 0xffff; e7 = iv.w >> 16;
        }
        uint4 v[8];
        v[0] = *(const uint4*)(q + e0 * FH + c * 8);
        v[1] = *(const uint4*)(q + e1 * FH + c * 8);
        v[2] = *(const uint4*)(q + e2 * FH + c * 8);
        v[3] = *(const uint4*)(q + e3 * FH + c * 8);
        v[4] = *(const uint4*)(q + e4 * FH + c * 8);
        v[5] = *(const uint4*)(q + e5 * FH + c * 8);
        v[6] = *(const uint4*)(q + e6 * FH + c * 8);
        v[7] = *(const uint4*)(q + e7 * FH + c * 8);

        unsigned ax = 0xFC00FC00u, ay = 0xFC00FC00u, az = 0xFC00FC00u, aw = 0xFC00FC00u;
#pragma unroll
        for (int k = 0; k < 8; ++k) {
            ax = pkmax(ax, v[k].x);
            ay = pkmax(ay, v[k].y);
            az = pkmax(az, v[k].z);
            aw = pkmax(aw, v[k].w);
        }
#pragma unroll
        for (int st = SL; st < LPP; st <<= 1) {
            ax = pkmax(ax, (unsigned)__shfl_xor((int)ax, st, 64));
            ay = pkmax(ay, (unsigned)__shfl_xor((int)ay, st, 64));
            az = pkmax(az, (unsigned)__shfl_xor((int)az, st, 64));
            aw = pkmax(aw, (unsigned)__shfl_xor((int)aw, st, 64));
        }
        if (g == 0) {
            uint4 r; r.x = ax; r.y = ay; r.z = az; r.w = aw;
            m_lds[lp * SL + c] = r;
        }
    }
    __syncthreads();

    if constexpr (WRITEX) {
        if (threadIdx.x < TILE * 4) {
            int pt  = threadIdx.x >> 2;
            int qtr = threadIdx.x & 3;
            int p   = pbase + pt;
            float p0 = pos[3 * p + 0];
            float p1 = pos[3 * p + 1];
            float p2 = pos[3 * p + 2];

            float h[FH];
#pragma unroll
            for (int s = 0; s < SL; ++s) {
                uint4 vv = m_lds[pt * SL + s];
                unsigned w4[4] = {vv.x, vv.y, vv.z, vv.w};
#pragma unroll
                for (int k = 0; k < 4; ++k) {
                    float2 f = __half22float2(*(__half2*)&w4[k]);
                    h[s * 8 + k * 2 + 0] = f.x;
                    h[s * 8 + k * 2 + 1] = f.y;
                }
            }
#pragma unroll
            for (int ch = 0; ch < FH; ++ch) {
                float gg = p0 * wap[ch] + p1 * wap[FH + ch] + p2 * wap[2 * FH + ch];
                h[ch] = celu1(h[ch] - gg);
            }
            float x[8];
#pragma unroll
            for (int j = 0; j < 8; ++j) {
                int c2 = qtr * 8 + j;
                float a = bb[c2];
#pragma unroll
                for (int ch = 0; ch < FH; ++ch)
                    a = fmaf(h[ch], wb[ch * FOUT + c2], a);
                x[j] = celu1(a);
            }
            int oldp = order[p];
            float4* xo = (float4*)(xout + (long long)oldp * FOUT + qtr * 8);
            xo[0] = make_float4(x[0], x[1], x[2], x[3]);
            xo[1] = make_float4(x[4], x[5], x[6], x[7]);
        }
    } else {
        // x phase: QW lanes per point, FOUT/QW outputs each, staged in LDS.
        constexpr int XS = FOUT / QW;
        float p0 = 0.f, p1 = 0.f, p2 = 0.f;
        int pt = threadIdx.x / QW;
        int qq = threadIdx.x % QW;
        if (threadIdx.x < TILE * QW) {
            int p = pbase + pt;
            p0 = pos[3 * p + 0];
            p1 = pos[3 * p + 1];
            p2 = pos[3 * p + 2];
            float h[FH];
#pragma unroll
            for (int s = 0; s < SL; ++s) {
                uint4 vv = m_lds[pt * SL + s];
                unsigned w4[4] = {vv.x, vv.y, vv.z, vv.w};
#pragma unroll
                for (int k = 0; k < 4; ++k) {
                    float2 f = __half22float2(*(__half2*)&w4[k]);
                    h[s * 8 + k * 2 + 0] = f.x;
                    h[s * 8 + k * 2 + 1] = f.y;
                }
            }
#pragma unroll
            for (int ch = 0; ch < FH; ++ch) {
                float gg = p0 * wap[ch] + p1 * wap[FH + ch] + p2 * wap[2 * FH + ch];
                h[ch] = celu1(h[ch] - gg);
            }
#pragma unroll
            for (int j = 0; j < XS; ++j) {
                int c2 = qq * XS + j;
                float a = bb[c2];
#pragma unroll
                for (int ch = 0; ch < FH; ++ch)
                    a = fmaf(h[ch], wb[ch * FOUT + c2], a);
                x_lds[pt * (FOUT + 1) + c2] = celu1(a);
            }
        }
        __syncthreads();
        // qn phase: QW lanes per point, FHN/QW (=8) channels each.
        if constexpr (FHN > 0) {
            if (threadIdx.x < TILE * QW) {
                int p = pbase + pt;
                float x[FOUT];
#pragma unroll
                for (int c2 = 0; c2 < FOUT; ++c2)
                    x[c2] = x_lds[pt * (FOUT + 1) + c2];
                float qn[8];
#pragma unroll
                for (int k = 0; k < 8; ++k) {
                    int cn = qq * 8 + k;
                    float a = ban[cn];
#pragma unroll
                    for (int c2 = 0; c2 < FOUT; ++c2)
                        a = fmaf(x[c2], wan[c2 * FHN + cn], a);
                    a = fmaf(p0, wan[(FOUT + 0) * FHN + cn], a);
                    a = fmaf(p1, wan[(FOUT + 1) * FHN + cn], a);
                    a = fmaf(p2, wan[(FOUT + 2) * FHN + cn], a);
                    qn[k] = a;
                }
                uint4 pk;
                pk.x = pack2(qn[0], qn[1]);
                pk.y = pack2(qn[2], qn[3]);
                pk.z = pack2(qn[4], qn[5]);
                pk.w = pack2(qn[6], qn[7]);
                *(uint4*)(qnext + p * FHN + qq * 8) = pk;
            }
        }
    }
}

extern "C" void kernel_launch(void* const* d_in, const int* in_sizes, int n_in,
                              void* d_out, int out_size, void* d_ws, size_t ws_size,
                              hipStream_t stream) {
    const float* pos = (const float*)d_in[0];
    const int* idx = (const int*)d_in[4];
    const float* w1a = (const float*)d_in[5];
    const float* b1a = (const float*)d_in[6];
    const float* w1b = (const float*)d_in[7];
    const float* b1b = (const float*)d_in[8];
    const float* w2a = (const float*)d_in[9];
    const float* b2a = (const float*)d_in[10];
    const float* w2b = (const float*)d_in[11];
    const float* b2b = (const float*)d_in[12];
    const float* w3a = (const float*)d_in[13];
    const float* b3a = (const float*)d_in[14];
    const float* w3b = (const float*)d_in[15];
    const float* b3b = (const float*)d_in[16];
    float* out = (float*)d_out;

    char* ws = (char*)d_ws;
    __half* A      = (__half*)ws;                         // 0..4MB: Q1 then Q3
    __half* B      = (__half*)(ws + (4u << 20));          // 4..6MB: Q2
    unsigned short* idxs = (unsigned short*)(ws + (6u << 20)); // 6..14MB
    int*    cid    = (int*)(ws + (14u << 20));            // 256KB
    int*    order  = (int*)(ws + (14u << 20) + (256u << 10)); // 256KB
    unsigned short* perm = (unsigned short*)(ws + (14u << 20) + (512u << 10)); // 128KB
    int*    hist   = (int*)(ws + (14u << 20) + (640u << 10));   // 16KB
    int*    cellptr= (int*)(ws + (14u << 20) + (656u << 10));   // 16KB
    float*  pos_s  = (float*)(ws + (15u << 20));          // 768KB

    hipMemsetAsync(hist, 0, NCELL * sizeof(int), stream);
    k_cell<<<NPTS / 256, 256, 0, stream>>>(pos, out, out_size, cid, hist);
    k_scan<<<1, 64, 0, stream>>>(hist, cellptr);
    k_scatter<<<NPTS / 256, 256, 0, stream>>>(pos, cid, cellptr, perm, order,
                                              pos_s, w1a, b1a, A);

    // layer 1 (FUSED with idx translation): FH=8 -> FOUT=8, emits Q2 + idxs
    k_layer<8, 8, 16, false, true><<<NPTS / TILE, 256, 0, stream>>>(
        A, nullptr, idx, idxs, perm, pos_s, order,
        w1a + 3 * 8, w1b, b1b, w2a, b2a, nullptr, B);
    // layer 2: FH=16 -> FOUT=16, emits Q3 into A
    k_layer<16, 16, 32, false, false><<<NPTS / TILE, 256, 0, stream>>>(
        B, idxs, nullptr, nullptr, nullptr, pos_s, nullptr,
        w2a + 8 * 16, w2b, b2b, w3a, b3a, nullptr, A);
    // layer 3: FH=32 -> FOUT=32, writes final x into d_out (old-id rows)
    k_layer<32, 32, 0, true, false><<<NPTS / TILE, 256, 0, stream>>>(
        A, idxs, nullptr, nullptr, nullptr, pos_s, order,
        w3a + 16 * 32, w3b, b3b, nullptr, nullptr, out + 3 * NPTS, nullptr);
}